// Round 10
// baseline (155.834 us; speedup 1.0000x reference)
//
#include <hip/hip_runtime.h>
#include <hip/hip_bf16.h>
#include <cstddef>

// Shapes (fixed by the problem)
#define BB 8
#define TT 512
#define CC 512
#define NHH 8
#define HDD 64

typedef __attribute__((ext_vector_type(8))) short short8;
typedef __attribute__((ext_vector_type(4))) float f32x4;

__device__ __forceinline__ unsigned short f2bf(float f) {
    unsigned u = __float_as_uint(f);
    u += 0x7FFFu + ((u >> 16) & 1u);
    return (unsigned short)(u >> 16);
}
__device__ __forceinline__ float bf2f(unsigned short h) {
    return __uint_as_float(((unsigned)h) << 16);
}

// ---------------------------------------------------------------------------
// Kernel 0: fused fp32 -> bf16 convert for x / w_attn / w_proj / rel.
// ---------------------------------------------------------------------------
__global__ __launch_bounds__(256) void cvt_all_k(
    const float* __restrict__ x, const float* __restrict__ wa,
    const float* __restrict__ wp, const float* __restrict__ rel,
    unsigned short* __restrict__ Xb, unsigned short* __restrict__ Wqb,
    unsigned short* __restrict__ Wpb, unsigned short* __restrict__ Relb)
{
    const int bidx = blockIdx.x;
    const float* in;
    unsigned short* out;
    int base;
    if (bidx < 2048)      { in = x;   out = Xb;   base = bidx; }
    else if (bidx < 2816) { in = wa;  out = Wqb;  base = bidx - 2048; }
    else if (bidx < 3072) { in = wp;  out = Wpb;  base = bidx - 2816; }
    else                  { in = rel; out = Relb; base = bidx - 3072; }
    const int i = base * 1024 + threadIdx.x * 4;
    const float4 v = *(const float4*)(in + i);
    unsigned short tmp[4] = {f2bf(v.x), f2bf(v.y), f2bf(v.z), f2bf(v.w)};
    *(uint2*)(out + i) = *(const uint2*)tmp;
}

// ---------------------------------------------------------------------------
// Kernel 1: QKV GEMM via MFMA — R6-proven 128x128 tile, BK=64, 384 blocks.
//   q/k -> qkbuf bf16 [4096][1024]; v -> in-LDS transpose -> VT [b][h][d][t].
// ---------------------------------------------------------------------------
__global__ __launch_bounds__(256, 2) void gemm_qkv_mfma(
    const unsigned short* __restrict__ Xb, const unsigned short* __restrict__ Wb,
    const float* __restrict__ bias, unsigned short* __restrict__ qkbuf,
    unsigned short* __restrict__ VT)
{
    __shared__ __align__(16) unsigned short lds[128 * 136];

    const int tid = threadIdx.x;
    const int w = tid >> 6, lane = tid & 63;
    const int c = lane & 15, quad = lane >> 4;
    const int wm = w >> 1, wn = w & 1;
    const int bm = blockIdx.y * 128, bn = blockIdx.x * 128;

    const unsigned short* pp[8];
#pragma unroll
    for (int l = 0; l < 8; ++l) {
        const int ci = w * 8 + l;
        if (ci < 16) {
            const int m16 = ci >> 1, kk = ci & 1;
            pp[l] = Xb + (size_t)(bm + m16 * 16 + c) * 512 + kk * 32 + quad * 8;
        } else {
            const int cb = ci - 16, n16 = cb >> 1, kk = cb & 1;
            pp[l] = Wb + (size_t)(bn + n16 * 16 + c) * 512 + kk * 32 + quad * 8;
        }
    }

    f32x4 acc[4][4];
#pragma unroll
    for (int i = 0; i < 4; ++i)
#pragma unroll
        for (int j = 0; j < 4; ++j) acc[i][j] = (f32x4){0.f, 0.f, 0.f, 0.f};

    short8 pre[8];
#pragma unroll
    for (int l = 0; l < 8; ++l) pre[l] = *(const short8*)pp[l];

    for (int k0 = 0; k0 < 512; k0 += 64) {
        __syncthreads();
#pragma unroll
        for (int l = 0; l < 8; ++l)
            *(short8*)&lds[(w * 8 + l) * 512 + lane * 8] = pre[l];
        __syncthreads();
        if (k0 + 64 < 512) {
#pragma unroll
            for (int l = 0; l < 8; ++l)
                pre[l] = *(const short8*)(pp[l] + k0 + 64);
        }
#pragma unroll
        for (int kk = 0; kk < 2; ++kk) {
            short8 af[4], bfr[4];
#pragma unroll
            for (int i = 0; i < 4; ++i)
                af[i] = *(const short8*)&lds[((wm * 4 + i) * 2 + kk) * 512 + lane * 8];
#pragma unroll
            for (int j = 0; j < 4; ++j)
                bfr[j] = *(const short8*)&lds[(16 + (wn * 4 + j) * 2 + kk) * 512 + lane * 8];
#pragma unroll
            for (int i = 0; i < 4; ++i)
#pragma unroll
                for (int j = 0; j < 4; ++j)
                    acc[i][j] = __builtin_amdgcn_mfma_f32_16x16x32_bf16(
                        af[i], bfr[j], acc[i][j], 0, 0, 0);
        }
    }

    float bj[4];
#pragma unroll
    for (int j = 0; j < 4; ++j) bj[j] = bias[bn + wn * 64 + j * 16 + c];

    if (bn < 1024) {
#pragma unroll
        for (int i = 0; i < 4; ++i)
#pragma unroll
            for (int j = 0; j < 4; ++j) {
                const int n = bn + wn * 64 + j * 16 + c;
#pragma unroll
                for (int r = 0; r < 4; ++r) {
                    const int m = bm + wm * 64 + i * 16 + quad * 4 + r;
                    qkbuf[(size_t)m * 1024 + n] = f2bf(acc[i][j][r] + bj[j]);
                }
            }
    } else {
        __syncthreads();
#pragma unroll
        for (int i = 0; i < 4; ++i)
#pragma unroll
            for (int j = 0; j < 4; ++j) {
                const int col = wn * 64 + j * 16 + c;
                const int row0 = wm * 64 + i * 16 + quad * 4;
                unsigned short t4[4];
#pragma unroll
                for (int r = 0; r < 4; ++r) t4[r] = f2bf(acc[i][j][r] + bj[j]);
                *(uint2*)&lds[col * 136 + row0] = *(const uint2*)t4;
            }
        __syncthreads();
        const int bi = bm >> 9, tb = bm & 511;
        const int hd0 = bn - 1024;
#pragma unroll
        for (int l = 0; l < 8; ++l) {
            const int idx = l * 256 + tid;
            const int col = idx >> 4, grp = idx & 15;
            const short8 v = *(const short8*)&lds[col * 136 + grp * 8];
            const int hd = hd0 + col, h = hd >> 6, d = hd & 63;
            *(short8*)(VT + ((size_t)(bi * NHH + h) * HDD + d) * TT + tb + grp * 8) = v;
        }
    }
}

// ---------------------------------------------------------------------------
// Kernel 2: LayerNorm over C=512 on q and k (bf16 in, bf16 head-major out).
// ---------------------------------------------------------------------------
__global__ __launch_bounds__(256) void ln_k(
    const unsigned short* __restrict__ qkbuf,
    const float* __restrict__ qg, const float* __restrict__ qb,
    const float* __restrict__ kg, const float* __restrict__ kb,
    unsigned short* __restrict__ Qh, unsigned short* __restrict__ Kh)
{
    const int wv = threadIdx.x >> 6, lane = threadIdx.x & 63;
    const int row = blockIdx.x * 4 + wv;
    const int bi = row >> 9, t = row & 511;
    const unsigned short* base = qkbuf + (size_t)row * 1024;

#pragma unroll
    for (int s = 0; s < 2; ++s) {
        const short8 v8 = *(const short8*)(base + s * 512 + lane * 8);
        float vf[8];
#pragma unroll
        for (int i = 0; i < 8; ++i) vf[i] = bf2f(((const unsigned short*)&v8)[i]);
        float sum = 0.f, sq = 0.f;
#pragma unroll
        for (int i = 0; i < 8; ++i) { sum += vf[i]; sq += vf[i] * vf[i]; }
#pragma unroll
        for (int off = 1; off < 64; off <<= 1) {
            sum += __shfl_xor(sum, off);
            sq += __shfl_xor(sq, off);
        }
        const float mu = sum * (1.f / 512.f);
        const float var = sq * (1.f / 512.f) - mu * mu;
        const float rsg = rsqrtf(var + 1e-5f);
        const float* gam = (s ? kg : qg) + lane * 8;
        const float* bet = (s ? kb : qb) + lane * 8;
        const float4 g0 = *(const float4*)gam, g1 = *(const float4*)(gam + 4);
        const float4 b0 = *(const float4*)bet, b1 = *(const float4*)(bet + 4);
        const float gv[8] = {g0.x, g0.y, g0.z, g0.w, g1.x, g1.y, g1.z, g1.w};
        const float bv[8] = {b0.x, b0.y, b0.z, b0.w, b1.x, b1.y, b1.z, b1.w};
        unsigned short o8[8];
#pragma unroll
        for (int i = 0; i < 8; ++i)
            o8[i] = f2bf((vf[i] - mu) * rsg * gv[i] + bv[i]);
        unsigned short* outp = s ? Kh : Qh;
        *(short8*)(outp + ((size_t)(bi * NHH + (lane >> 3)) * TT + t) * HDD
                   + (lane & 7) * 8) = *(const short8*)o8;
    }
}

// ---------------------------------------------------------------------------
// Kernel 3: barrier-free MFMA flash attention, k-tile 128, software-pipelined
//   RD (R10). The rel-window loads for iteration it+1 are issued at the TOP of
//   iteration it (held in registers); their MFMA + circular LDS writes happen
//   AFTER PV — so rel-load latency and the RD->gather dependency are off the
//   per-iteration critical path (gather -> softmax -> Ps -> PV only).
//   Circular RD indexed by delta & 255 (same collision-free algebra as R9:
//   writes land after the only gather that reads the overwritten range).
// ---------------------------------------------------------------------------
#define RD_FULL(nr_, mb_)                                                       \
    {                                                                           \
        int mrow = (mb_) + (nr_) * 16 + c;                                      \
        mrow = mrow < 0 ? 0 : (mrow > 511 ? 511 : mrow);                        \
        const unsigned short* gp = Rbase + (size_t)mrow * CC + quad * 8;        \
        const short8 br0 = *(const short8*)gp;                                  \
        const short8 br1 = *(const short8*)(gp + 32);                           \
        f32x4 a2 = (f32x4){0.f, 0.f, 0.f, 0.f};                                 \
        a2 = __builtin_amdgcn_mfma_f32_16x16x32_bf16(aq0, br0, a2, 0, 0, 0);    \
        a2 = __builtin_amdgcn_mfma_f32_16x16x32_bf16(aq1, br1, a2, 0, 0, 0);    \
        const int colw = ((mb_) + (nr_) * 16 + c) & 255;                        \
        _Pragma("unroll")                                                       \
        for (int r = 0; r < 4; ++r)                                             \
            RDs[w][(quad * 4 + r) * 260 + colw] = f2bf(a2[r]);                  \
    }

__global__ __launch_bounds__(256, 2) void attn_k(
    const unsigned short* __restrict__ Qh, const unsigned short* __restrict__ Kh,
    const unsigned short* __restrict__ VT, const unsigned short* __restrict__ Relb,
    unsigned short* __restrict__ Yb)
{
    __shared__ __align__(16) unsigned short Ps[4][16 * 136];   // 128 cols + pad
    __shared__ __align__(16) unsigned short RDs[4][16 * 260];  // 256 circ + pad

    const int tid = threadIdx.x;
    const int w = tid >> 6;
    const int lane = tid & 63;
    const int c = lane & 15;
    const int quad = lane >> 4;

    // pairing-robust balanced decode (R6-proven)
    const int bid = blockIdx.x;
    const int bit0 = bid & 1, bit8 = (bid >> 8) & 1;
    const int s_ = bit0 ^ bit8;
    const int q0 = (bid >> 1) & 7;
    const int qt = s_ ? 7 - q0 : q0;
    const int h = (bid >> 4) & 7;
    const int b = ((bid >> 7) & 1) | (bit8 << 1) | (bit0 << 2);
    const int i0 = qt * 64;

    const unsigned short* Kbase = Kh + (size_t)(b * NHH + h) * TT * HDD;
    const unsigned short* Vbase = VT + (size_t)(b * NHH + h) * HDD * TT;
    const unsigned short* Rbase = Relb + h * HDD;

    // Q A-fragments: direct per-lane loads
    const unsigned short* qp = Qh + (size_t)(b * NHH + h) * TT * HDD
                               + (size_t)(i0 + w * 16 + c) * HDD + quad * 8;
    const short8 aq0 = *(const short8*)qp;
    const short8 aq1 = *(const short8*)(qp + 32);

    f32x4 oacc[4];
    float m_i[4], l_i[4];
#pragma unroll
    for (int r = 0; r < 4; ++r) { m_i[r] = -1e30f; l_i[r] = 0.f; }
#pragma unroll
    for (int nd = 0; nd < 4; ++nd) oacc[nd] = (f32x4){0.f, 0.f, 0.f, 0.f};

    // preloop: seed deltas [i0+1, i0+65) and iter-0's window [i0-127, i0+1)
    {
        const int mb0 = i0 + 1;
#pragma unroll
        for (int nr = 0; nr < 4; ++nr) RD_FULL(nr, mb0)
        const int mb1 = i0 - 127;
#pragma unroll
        for (int nr = 0; nr < 8; ++nr) RD_FULL(nr, mb1)
    }

    const int nIter = (qt + 2) >> 1;
    short8 rl0[8], rl1[8];   // prefetched rel rows for next iteration's window

    for (int it = 0; it < nIter; ++it) {
        const int j0 = it * 128;
        const int lim = i0 + 63 - j0;                 // >= 0 within loop
        const int nsM = (lim >> 4) >= 7 ? 8 : (lim >> 4) + 1;
        const int kkM = (lim >> 5) >= 3 ? 4 : (lim >> 5) + 1;
        const bool haveNext = (it + 1) < nIter;
        const int mbn = i0 - (it + 1) * 128 - 127;

        // (1) issue next window's rel loads early (latency hidden by S+softmax)
        if (haveNext) {
#pragma unroll
            for (int nr = 0; nr < 8; ++nr) {
                int mrow = mbn + nr * 16 + c;
                mrow = mrow < 0 ? 0 : (mrow > 511 ? 511 : mrow);
                const unsigned short* gp = Rbase + (size_t)mrow * CC + quad * 8;
                rl0[nr] = *(const short8*)gp;
                rl1[nr] = *(const short8*)(gp + 32);
            }
        }

        // (2) S = Q @ K^T + rel gather, scale, causal mask
        const int dbase = i0 - j0;
        float sc[8][4];
#pragma unroll
        for (int ns = 0; ns < 8; ++ns) {
            if (ns < nsM) {
                const unsigned short* kp =
                    Kbase + (size_t)(j0 + ns * 16 + c) * HDD + quad * 8;
                const short8 bk0 = *(const short8*)kp;
                const short8 bk1 = *(const short8*)(kp + 32);
                f32x4 a2 = (f32x4){0.f, 0.f, 0.f, 0.f};
                a2 = __builtin_amdgcn_mfma_f32_16x16x32_bf16(aq0, bk0, a2, 0, 0, 0);
                a2 = __builtin_amdgcn_mfma_f32_16x16x32_bf16(aq1, bk1, a2, 0, 0, 0);
                const int jc = ns * 16 + c;
#pragma unroll
                for (int r = 0; r < 4; ++r) {
                    const int r16 = quad * 4 + r;
                    const int dp = (dbase + w * 16 + r16 - jc) & 255;
                    const float rdv = bf2f(RDs[w][r16 * 260 + dp]);
                    const float v = (a2[r] + rdv) * 0.125f;
                    sc[ns][r] = (j0 + jc > i0 + w * 16 + r16) ? -1e30f : v;
                }
            }
        }

        // (3) online softmax over up to 128 columns
        float alpha[4];
#pragma unroll
        for (int r = 0; r < 4; ++r) {
            float m = -1e30f;
#pragma unroll
            for (int ns = 0; ns < 8; ++ns)
                if (ns < nsM) m = fmaxf(m, sc[ns][r]);
#pragma unroll
            for (int off = 1; off < 16; off <<= 1) m = fmaxf(m, __shfl_xor(m, off));
            const float mn = fmaxf(m_i[r], m);
            alpha[r] = __expf(m_i[r] - mn);
            m_i[r] = mn;
        }
        float rs[4] = {0.f, 0.f, 0.f, 0.f};
#pragma unroll
        for (int ns = 0; ns < 8; ++ns) {
#pragma unroll
            for (int r = 0; r < 4; ++r) {
                unsigned short pv = 0;
                if (ns < nsM) {
                    const float p = __expf(sc[ns][r] - m_i[r]);
                    rs[r] += p;
                    pv = f2bf(p);
                }
                Ps[w][(quad * 4 + r) * 136 + ns * 16 + c] = pv;
            }
        }
#pragma unroll
        for (int r = 0; r < 4; ++r) {
#pragma unroll
            for (int off = 1; off < 16; off <<= 1) rs[r] += __shfl_xor(rs[r], off);
            l_i[r] = l_i[r] * alpha[r] + rs[r];
        }
#pragma unroll
        for (int nd = 0; nd < 4; ++nd)
#pragma unroll
            for (int r = 0; r < 4; ++r) oacc[nd][r] *= alpha[r];

        // (4) O += P @ V : up to 4 k-steps of 32, skip fully-masked steps
#pragma unroll
        for (int kk = 0; kk < 4; ++kk) {
            if (kk < kkM) {
                const short8 ap =
                    *(const short8*)&Ps[w][c * 136 + kk * 32 + quad * 8];
#pragma unroll
                for (int nd = 0; nd < 4; ++nd) {
                    const unsigned short* vp =
                        Vbase + (size_t)(nd * 16 + c) * TT + j0 + kk * 32 + quad * 8;
                    const short8 bv = *(const short8*)vp;
                    oacc[nd] = __builtin_amdgcn_mfma_f32_16x16x32_bf16(
                        ap, bv, oacc[nd], 0, 0, 0);
                }
            }
        }

        // (5) next window's RD math + circular LDS writes (loads landed by now)
        if (haveNext) {
#pragma unroll
            for (int nr = 0; nr < 8; ++nr) {
                f32x4 a2 = (f32x4){0.f, 0.f, 0.f, 0.f};
                a2 = __builtin_amdgcn_mfma_f32_16x16x32_bf16(aq0, rl0[nr], a2, 0, 0, 0);
                a2 = __builtin_amdgcn_mfma_f32_16x16x32_bf16(aq1, rl1[nr], a2, 0, 0, 0);
                const int colw = (mbn + nr * 16 + c) & 255;
#pragma unroll
                for (int r = 0; r < 4; ++r)
                    RDs[w][(quad * 4 + r) * 260 + colw] = f2bf(a2[r]);
            }
        }
    }

    // epilogue: Yb[b][t][h*64 + d] bf16
#pragma unroll
    for (int r = 0; r < 4; ++r) {
        const float inv = 1.f / l_i[r];
        const int trow = i0 + w * 16 + quad * 4 + r;
        unsigned short* yb = Yb + ((size_t)b * TT + trow) * CC + h * HDD;
#pragma unroll
        for (int nd = 0; nd < 4; ++nd)
            yb[nd * 16 + c] = f2bf(oacc[nd][r] * inv);
    }
}

// ---------------------------------------------------------------------------
// Kernel 4: out = Yb @ Wpb^T + b_proj via MFMA (R4/R6-proven).
// ---------------------------------------------------------------------------
__global__ __launch_bounds__(256, 2) void gemm_proj_mfma(
    const unsigned short* __restrict__ Yb, const unsigned short* __restrict__ Wp,
    const float* __restrict__ bias, float* __restrict__ out)
{
    __shared__ __align__(16) unsigned short lds[24 * 512];

    const int tid = threadIdx.x;
    const int w = tid >> 6, lane = tid & 63;
    const int c = lane & 15, quad = lane >> 4;
    const int wm = w >> 1, wn = w & 1;
    const int bm = blockIdx.y * 64, bn = blockIdx.x * 128;

    const unsigned short* pp[6];
#pragma unroll
    for (int l = 0; l < 6; ++l) {
        const int ci = w * 6 + l;
        if (ci < 8) {
            const int m16 = ci >> 1, kk = ci & 1;
            pp[l] = Yb + (size_t)(bm + m16 * 16 + c) * 512 + kk * 32 + quad * 8;
        } else {
            const int cb = ci - 8, n16 = cb >> 1, kk = cb & 1;
            pp[l] = Wp + (size_t)(bn + n16 * 16 + c) * 512 + kk * 32 + quad * 8;
        }
    }

    f32x4 acc[2][4];
#pragma unroll
    for (int i = 0; i < 2; ++i)
#pragma unroll
        for (int j = 0; j < 4; ++j) acc[i][j] = (f32x4){0.f, 0.f, 0.f, 0.f};

    short8 pre[6];
#pragma unroll
    for (int l = 0; l < 6; ++l) pre[l] = *(const short8*)pp[l];

    for (int k0 = 0; k0 < 512; k0 += 64) {
        __syncthreads();
#pragma unroll
        for (int l = 0; l < 6; ++l)
            *(short8*)&lds[(w * 6 + l) * 512 + lane * 8] = pre[l];
        __syncthreads();
        if (k0 + 64 < 512) {
#pragma unroll
            for (int l = 0; l < 6; ++l)
                pre[l] = *(const short8*)(pp[l] + k0 + 64);
        }
#pragma unroll
        for (int kk = 0; kk < 2; ++kk) {
            short8 af[2], bfr[4];
#pragma unroll
            for (int i = 0; i < 2; ++i)
                af[i] = *(const short8*)&lds[((wm * 2 + i) * 2 + kk) * 512 + lane * 8];
#pragma unroll
            for (int j = 0; j < 4; ++j)
                bfr[j] = *(const short8*)&lds[(8 + (wn * 4 + j) * 2 + kk) * 512 + lane * 8];
#pragma unroll
            for (int i = 0; i < 2; ++i)
#pragma unroll
                for (int j = 0; j < 4; ++j)
                    acc[i][j] = __builtin_amdgcn_mfma_f32_16x16x32_bf16(
                        af[i], bfr[j], acc[i][j], 0, 0, 0);
        }
    }

#pragma unroll
    for (int j = 0; j < 4; ++j) {
        const int n = bn + wn * 64 + j * 16 + c;
        const float bj = bias[n];
#pragma unroll
        for (int i = 0; i < 2; ++i)
#pragma unroll
            for (int r = 0; r < 4; ++r) {
                const int m = bm + wm * 32 + i * 16 + quad * 4 + r;
                out[(size_t)m * 512 + n] = acc[i][j][r] + bj;
            }
    }
}

// ---------------------------------------------------------------------------
extern "C" void kernel_launch(void* const* d_in, const int* in_sizes, int n_in,
                              void* d_out, int out_size, void* d_ws, size_t ws_size,
                              hipStream_t stream)
{
    const float* x      = (const float*)d_in[0];
    const float* w_attn = (const float*)d_in[1];
    const float* b_attn = (const float*)d_in[2];
    const float* w_proj = (const float*)d_in[3];
    const float* b_proj = (const float*)d_in[4];
    const float* q_g    = (const float*)d_in[5];
    const float* q_b    = (const float*)d_in[6];
    const float* k_g    = (const float*)d_in[7];
    const float* k_b    = (const float*)d_in[8];
    const float* rel    = (const float*)d_in[9];
    float* out = (float*)d_out;

    // workspace (~26.5 MB bf16): qkbuf [4096][1024] 8MB | Qh 4 | Kh 4 | VT 4 |
    //   Relb 0.5 | Xb 4 | Wqb 1.5 | Wpb 0.5.  Yb (4MB) aliases qkbuf.
    unsigned short* qkbuf = (unsigned short*)d_ws;
    unsigned short* Qh   = qkbuf + (size_t)4096 * 1024;
    unsigned short* Kh   = Qh + (size_t)4096 * 512;
    unsigned short* VT   = Kh + (size_t)4096 * 512;
    unsigned short* Relb = VT + (size_t)4096 * 512;
    unsigned short* Xb   = Relb + (size_t)512 * 512;
    unsigned short* Wqb  = Xb + (size_t)4096 * 512;
    unsigned short* Wpb  = Wqb + (size_t)1536 * 512;
    unsigned short* Yb   = qkbuf;

    cvt_all_k<<<3328, 256, 0, stream>>>(x, w_attn, w_proj, rel, Xb, Wqb, Wpb, Relb);
    gemm_qkv_mfma<<<dim3(12, 32), 256, 0, stream>>>(Xb, Wqb, b_attn, qkbuf, VT);
    ln_k<<<1024, 256, 0, stream>>>(qkbuf, q_g, q_b, k_g, k_b, Qh, Kh);
    attn_k<<<512, 256, 0, stream>>>(Qh, Kh, VT, Relb, Yb);
    gemm_proj_mfma<<<dim3(4, 64), 256, 0, stream>>>(Yb, Wpb, b_proj, out);
}

// Round 12
// 148.348 us; speedup vs baseline: 1.0505x; 1.0505x over previous
//
#include <hip/hip_runtime.h>
#include <hip/hip_bf16.h>
#include <cstddef>

// Shapes (fixed by the problem)
#define BB 8
#define TT 512
#define CC 512
#define NHH 8
#define HDD 64

typedef __attribute__((ext_vector_type(8))) short short8;
typedef __attribute__((ext_vector_type(4))) float f32x4;

__device__ __forceinline__ unsigned short f2bf(float f) {
    unsigned u = __float_as_uint(f);
    u += 0x7FFFu + ((u >> 16) & 1u);
    return (unsigned short)(u >> 16);
}
__device__ __forceinline__ float bf2f(unsigned short h) {
    return __uint_as_float(((unsigned)h) << 16);
}

// ---------------------------------------------------------------------------
// Kernel 0a: zero the LN-stats buffer (graph-safe; replaces hipMemsetAsync).
// ---------------------------------------------------------------------------
__global__ __launch_bounds__(256) void zero_stats_k(float* __restrict__ Stats)
{
    const int i = (blockIdx.x * 256 + threadIdx.x) * 4;
    *(float4*)(Stats + i) = make_float4(0.f, 0.f, 0.f, 0.f);
}

// ---------------------------------------------------------------------------
// Kernel 0: fused fp32 -> bf16 convert for x / w_attn / w_proj / rel.
// ---------------------------------------------------------------------------
__global__ __launch_bounds__(256) void cvt_all_k(
    const float* __restrict__ x, const float* __restrict__ wa,
    const float* __restrict__ wp, const float* __restrict__ rel,
    unsigned short* __restrict__ Xb, unsigned short* __restrict__ Wqb,
    unsigned short* __restrict__ Wpb, unsigned short* __restrict__ Relb)
{
    const int bidx = blockIdx.x;
    const float* in;
    unsigned short* out;
    int base;
    if (bidx < 2048)      { in = x;   out = Xb;   base = bidx; }
    else if (bidx < 2816) { in = wa;  out = Wqb;  base = bidx - 2048; }
    else if (bidx < 3072) { in = wp;  out = Wpb;  base = bidx - 2816; }
    else                  { in = rel; out = Relb; base = bidx - 3072; }
    const int i = base * 1024 + threadIdx.x * 4;
    const float4 v = *(const float4*)(in + i);
    unsigned short tmp[4] = {f2bf(v.x), f2bf(v.y), f2bf(v.z), f2bf(v.w)};
    *(uint2*)(out + i) = *(const uint2*)tmp;
}

// ---------------------------------------------------------------------------
// Kernel 1: QKV GEMM via MFMA (R6-proven 128x128) + LN-stats epilogue.
//   q/k -> qkbuf bf16 [4096][1024] AND per-row {sum, sumsq} atomics into
//   Stats[row][stream][2] (fp32, pre-zeroed). v -> in-LDS transpose -> VT.
// ---------------------------------------------------------------------------
__global__ __launch_bounds__(256, 2) void gemm_qkv_mfma(
    const unsigned short* __restrict__ Xb, const unsigned short* __restrict__ Wb,
    const float* __restrict__ bias, unsigned short* __restrict__ qkbuf,
    unsigned short* __restrict__ VT, float* __restrict__ Stats)
{
    __shared__ __align__(16) unsigned short lds[128 * 136];

    const int tid = threadIdx.x;
    const int w = tid >> 6, lane = tid & 63;
    const int c = lane & 15, quad = lane >> 4;
    const int wm = w >> 1, wn = w & 1;
    const int bm = blockIdx.y * 128, bn = blockIdx.x * 128;

    const unsigned short* pp[8];
#pragma unroll
    for (int l = 0; l < 8; ++l) {
        const int ci = w * 8 + l;
        if (ci < 16) {
            const int m16 = ci >> 1, kk = ci & 1;
            pp[l] = Xb + (size_t)(bm + m16 * 16 + c) * 512 + kk * 32 + quad * 8;
        } else {
            const int cb = ci - 16, n16 = cb >> 1, kk = cb & 1;
            pp[l] = Wb + (size_t)(bn + n16 * 16 + c) * 512 + kk * 32 + quad * 8;
        }
    }

    f32x4 acc[4][4];
#pragma unroll
    for (int i = 0; i < 4; ++i)
#pragma unroll
        for (int j = 0; j < 4; ++j) acc[i][j] = (f32x4){0.f, 0.f, 0.f, 0.f};

    short8 pre[8];
#pragma unroll
    for (int l = 0; l < 8; ++l) pre[l] = *(const short8*)pp[l];

    for (int k0 = 0; k0 < 512; k0 += 64) {
        __syncthreads();
#pragma unroll
        for (int l = 0; l < 8; ++l)
            *(short8*)&lds[(w * 8 + l) * 512 + lane * 8] = pre[l];
        __syncthreads();
        if (k0 + 64 < 512) {
#pragma unroll
            for (int l = 0; l < 8; ++l)
                pre[l] = *(const short8*)(pp[l] + k0 + 64);
        }
#pragma unroll
        for (int kk = 0; kk < 2; ++kk) {
            short8 af[4], bfr[4];
#pragma unroll
            for (int i = 0; i < 4; ++i)
                af[i] = *(const short8*)&lds[((wm * 4 + i) * 2 + kk) * 512 + lane * 8];
#pragma unroll
            for (int j = 0; j < 4; ++j)
                bfr[j] = *(const short8*)&lds[(16 + (wn * 4 + j) * 2 + kk) * 512 + lane * 8];
#pragma unroll
            for (int i = 0; i < 4; ++i)
#pragma unroll
                for (int j = 0; j < 4; ++j)
                    acc[i][j] = __builtin_amdgcn_mfma_f32_16x16x32_bf16(
                        af[i], bfr[j], acc[i][j], 0, 0, 0);
        }
    }

    float bj[4];
#pragma unroll
    for (int j = 0; j < 4; ++j) bj[j] = bias[bn + wn * 64 + j * 16 + c];

    if (bn < 1024) {
        // per-row partial LN stats over this block's 4 j-columns
        float sv[4][4], sq2[4][4];
#pragma unroll
        for (int i = 0; i < 4; ++i)
#pragma unroll
            for (int r = 0; r < 4; ++r) { sv[i][r] = 0.f; sq2[i][r] = 0.f; }
#pragma unroll
        for (int i = 0; i < 4; ++i)
#pragma unroll
            for (int j = 0; j < 4; ++j) {
                const int n = bn + wn * 64 + j * 16 + c;
#pragma unroll
                for (int r = 0; r < 4; ++r) {
                    const float v = acc[i][j][r] + bj[j];
                    sv[i][r] += v;
                    sq2[i][r] += v * v;
                    const int m = bm + wm * 64 + i * 16 + quad * 4 + r;
                    qkbuf[(size_t)m * 1024 + n] = f2bf(v);
                }
            }
        // butterfly over the 16 c-lanes (lane = quad*16+c, xor<16 stays in-quad)
#pragma unroll
        for (int off = 1; off < 16; off <<= 1)
#pragma unroll
            for (int i = 0; i < 4; ++i)
#pragma unroll
                for (int r = 0; r < 4; ++r) {
                    sv[i][r] += __shfl_xor(sv[i][r], off);
                    sq2[i][r] += __shfl_xor(sq2[i][r], off);
                }
        // lane c owns pair (i=c>>2, r=c&3): 2 atomics/lane, all lanes active
        const int ii = c >> 2, rr = c & 3;
        const int row = bm + wm * 64 + ii * 16 + quad * 4 + rr;
        const int strm = bn >> 9;   // 0 = q, 1 = k
        atomicAdd(&Stats[row * 4 + strm * 2 + 0], sv[ii][rr]);
        atomicAdd(&Stats[row * 4 + strm * 2 + 1], sq2[ii][rr]);
    } else {
        // v: bias + bf16, transpose in LDS -> VT[b][h][d][t]
        __syncthreads();
#pragma unroll
        for (int i = 0; i < 4; ++i)
#pragma unroll
            for (int j = 0; j < 4; ++j) {
                const int col = wn * 64 + j * 16 + c;
                const int row0 = wm * 64 + i * 16 + quad * 4;
                unsigned short t4[4];
#pragma unroll
                for (int r = 0; r < 4; ++r) t4[r] = f2bf(acc[i][j][r] + bj[j]);
                *(uint2*)&lds[col * 136 + row0] = *(const uint2*)t4;
            }
        __syncthreads();
        const int bi = bm >> 9, tb = bm & 511;
        const int hd0 = bn - 1024;
#pragma unroll
        for (int l = 0; l < 8; ++l) {
            const int idx = l * 256 + tid;
            const int col = idx >> 4, grp = idx & 15;
            const short8 v = *(const short8*)&lds[col * 136 + grp * 8];
            const int hd = hd0 + col, h = hd >> 6, d = hd & 63;
            *(short8*)(VT + ((size_t)(bi * NHH + h) * HDD + d) * TT + tb + grp * 8) = v;
        }
    }
}

// ---------------------------------------------------------------------------
// Kernel 3: MFMA flash attention (R6-proven structure) with INLINE LayerNorm
//   applied while staging Q/K fragments straight from qkbuf, using the
//   Stats sums from the QKV kernel. Circular RD (delta & 127), Relb bf16,
//   pairing-robust qt swizzle. Writes Yb bf16.
// ---------------------------------------------------------------------------
#define RD_BODY(nr_)                                                            \
    {                                                                           \
        const short8 br0 = *(const short8*)&Rels[((nr_) * 2 + 0) * 512 + lane * 8]; \
        const short8 br1 = *(const short8*)&Rels[((nr_) * 2 + 1) * 512 + lane * 8]; \
        f32x4 a2 = (f32x4){0.f, 0.f, 0.f, 0.f};                                 \
        a2 = __builtin_amdgcn_mfma_f32_16x16x32_bf16(aq0, br0, a2, 0, 0, 0);    \
        a2 = __builtin_amdgcn_mfma_f32_16x16x32_bf16(aq1, br1, a2, 0, 0, 0);    \
        const int colw = (mbase + (nr_) * 16 + c) & 127;                        \
        _Pragma("unroll")                                                       \
        for (int r = 0; r < 4; ++r)                                             \
            RDs[w][(quad * 4 + r) * 132 + colw] = f2bf(a2[r]);                  \
    }

__global__ __launch_bounds__(256, 2) void attn_k(
    const unsigned short* __restrict__ qkbuf, const unsigned short* __restrict__ VT,
    const unsigned short* __restrict__ Relb, const float* __restrict__ Stats,
    const float* __restrict__ qg, const float* __restrict__ qb,
    const float* __restrict__ kg, const float* __restrict__ kb,
    unsigned short* __restrict__ Yb)
{
    __shared__ __align__(16) unsigned short Qs[8 * 512];
    __shared__ __align__(16) unsigned short Ks[8 * 512];
    __shared__ __align__(16) unsigned short Vs[8 * 512];
    __shared__ __align__(16) unsigned short Rels[16 * 512];
    __shared__ __align__(16) unsigned short Ps[4][16 * 72];
    __shared__ __align__(16) unsigned short RDs[4][16 * 132];

    const int tid = threadIdx.x;
    const int w = tid >> 6;
    const int lane = tid & 63;
    const int c = lane & 15;
    const int quad = lane >> 4;

    // pairing-robust balanced decode (R6-proven)
    const int bid = blockIdx.x;
    const int bit0 = bid & 1, bit8 = (bid >> 8) & 1;
    const int s_ = bit0 ^ bit8;
    const int q0 = (bid >> 1) & 7;
    const int qt = s_ ? 7 - q0 : q0;
    const int h = (bid >> 4) & 7;
    const int b = ((bid >> 7) & 1) | (bit8 << 1) | (bit0 << 2);
    const int i0 = qt * 64;

    const unsigned short* Vbase = VT + (size_t)(b * NHH + h) * HDD * TT;
    const unsigned short* Rbase = Relb + h * HDD;

    // hoisted k-stream gamma/beta for this thread's 16 channels
    float kgv[2][8], kbv[2][8];
#pragma unroll
    for (int kk = 0; kk < 2; ++kk)
#pragma unroll
        for (int e = 0; e < 8; ++e) {
            const int chan = h * 64 + kk * 32 + quad * 8 + e;
            kgv[kk][e] = kg[chan];
            kbv[kk][e] = kb[chan];
        }

    // stage Q tile once, LN applied inline
    {
        const int trow = i0 + w * 16 + c;
        const float2 st = *(const float2*)&Stats[(b * 512 + trow) * 4 + 0];
        const float mu = st.x * (1.f / 512.f);
        const float var = st.y * (1.f / 512.f) - mu * mu;
        const float rsg = rsqrtf(var + 1e-5f);
#pragma unroll
        for (int kk = 0; kk < 2; ++kk) {
            const unsigned short* gp = qkbuf + (size_t)(b * 512 + trow) * 1024
                                       + h * 64 + kk * 32 + quad * 8;
            const short8 raw = *(const short8*)gp;
            unsigned short o8[8];
#pragma unroll
            for (int e = 0; e < 8; ++e) {
                const int chan = h * 64 + kk * 32 + quad * 8 + e;
                o8[e] = f2bf((bf2f(((const unsigned short*)&raw)[e]) - mu) * rsg
                             * qg[chan] + qb[chan]);
            }
            *(short8*)&Qs[(w * 2 + kk) * 512 + lane * 8] = *(const short8*)o8;
        }
    }

    f32x4 oacc[4];
    float m_i[4], l_i[4];
#pragma unroll
    for (int r = 0; r < 4; ++r) { m_i[r] = -1e30f; l_i[r] = 0.f; }
#pragma unroll
    for (int nd = 0; nd < 4; ++nd) oacc[nd] = (f32x4){0.f, 0.f, 0.f, 0.f};

    short8 aq0, aq1;

    for (int jt = 0; jt <= qt; ++jt) {
        const int j0 = jt * 64;
        // stage K tile with inline LN
        {
            const int krow = j0 + w * 16 + c;
            const float2 st = *(const float2*)&Stats[(b * 512 + krow) * 4 + 2];
            const float mu = st.x * (1.f / 512.f);
            const float var = st.y * (1.f / 512.f) - mu * mu;
            const float rsg = rsqrtf(var + 1e-5f);
#pragma unroll
            for (int kk = 0; kk < 2; ++kk) {
                const unsigned short* gp = qkbuf + (size_t)(b * 512 + krow) * 1024
                                           + 512 + h * 64 + kk * 32 + quad * 8;
                const short8 raw = *(const short8*)gp;
                unsigned short o8[8];
#pragma unroll
                for (int e = 0; e < 8; ++e)
                    o8[e] = f2bf((bf2f(((const unsigned short*)&raw)[e]) - mu) * rsg
                                 * kgv[kk][e] + kbv[kk][e]);
                *(short8*)&Ks[(w * 2 + kk) * 512 + lane * 8] = *(const short8*)o8;
            }
        }
#pragma unroll
        for (int js = 0; js < 2; ++js) {
            const unsigned short* gp =
                Vbase + (size_t)(w * 16 + c) * TT + j0 + js * 32 + quad * 8;
            *(short8*)&Vs[(w * 2 + js) * 512 + lane * 8] = *(const short8*)gp;
        }
        // rel window staging: first iter 128 deltas, later 64 new
        const int mbase = i0 - j0 - 63;
        if (jt == 0) {
#pragma unroll
            for (int sb = 0; sb < 2; ++sb) {
#pragma unroll
                for (int kk = 0; kk < 2; ++kk) {
                    const int n16 = w * 2 + sb;
                    int mrow = mbase + n16 * 16 + c;
                    mrow = mrow < 0 ? 0 : (mrow > 511 ? 511 : mrow);
                    *(short8*)&Rels[(n16 * 2 + kk) * 512 + lane * 8] =
                        *(const short8*)(Rbase + (size_t)mrow * CC + kk * 32 + quad * 8);
                }
            }
        } else {
#pragma unroll
            for (int kk = 0; kk < 2; ++kk) {
                int mrow = mbase + w * 16 + c;
                mrow = mrow < 0 ? 0 : (mrow > 511 ? 511 : mrow);
                *(short8*)&Rels[(w * 2 + kk) * 512 + lane * 8] =
                    *(const short8*)(Rbase + (size_t)mrow * CC + kk * 32 + quad * 8);
            }
        }
        __syncthreads();

        if (jt == 0) {
            aq0 = *(const short8*)&Qs[(w * 2 + 0) * 512 + lane * 8];
            aq1 = *(const short8*)&Qs[(w * 2 + 1) * 512 + lane * 8];
        }

        // S = Q @ K^T
        f32x4 sAcc[4];
#pragma unroll
        for (int ns = 0; ns < 4; ++ns) {
            const short8 bk0 = *(const short8*)&Ks[(ns * 2 + 0) * 512 + lane * 8];
            const short8 bk1 = *(const short8*)&Ks[(ns * 2 + 1) * 512 + lane * 8];
            f32x4 a2 = (f32x4){0.f, 0.f, 0.f, 0.f};
            a2 = __builtin_amdgcn_mfma_f32_16x16x32_bf16(aq0, bk0, a2, 0, 0, 0);
            a2 = __builtin_amdgcn_mfma_f32_16x16x32_bf16(aq1, bk1, a2, 0, 0, 0);
            sAcc[ns] = a2;
        }
        // RD: only new delta subtiles
        if (jt == 0) {
#pragma unroll
            for (int nr = 0; nr < 8; ++nr) RD_BODY(nr)
        } else {
#pragma unroll
            for (int nr = 0; nr < 4; ++nr) RD_BODY(nr)
        }

        // gather rel bias (circular col = delta & 127), scale, causal mask
        const int dbase = i0 - j0;
        float sc[4][4];
#pragma unroll
        for (int ns = 0; ns < 4; ++ns) {
#pragma unroll
            for (int r = 0; r < 4; ++r) {
                const int r16 = quad * 4 + r;
                const int jc = ns * 16 + c;
                const int dp = (dbase + w * 16 + r16 - jc) & 127;
                const float rdv = bf2f(RDs[w][r16 * 132 + dp]);
                const float v = (sAcc[ns][r] + rdv) * 0.125f;
                sc[ns][r] = (j0 + jc > i0 + w * 16 + r16) ? -1e30f : v;
            }
        }
        float alpha[4];
#pragma unroll
        for (int r = 0; r < 4; ++r) {
            float m = fmaxf(fmaxf(sc[0][r], sc[1][r]), fmaxf(sc[2][r], sc[3][r]));
#pragma unroll
            for (int off = 1; off < 16; off <<= 1) m = fmaxf(m, __shfl_xor(m, off));
            const float mn = fmaxf(m_i[r], m);
            alpha[r] = __expf(m_i[r] - mn);
            m_i[r] = mn;
        }
        float rs[4] = {0.f, 0.f, 0.f, 0.f};
#pragma unroll
        for (int ns = 0; ns < 4; ++ns) {
#pragma unroll
            for (int r = 0; r < 4; ++r) {
                const float p = __expf(sc[ns][r] - m_i[r]);
                rs[r] += p;
                Ps[w][(quad * 4 + r) * 72 + ns * 16 + c] = f2bf(p);
            }
        }
#pragma unroll
        for (int r = 0; r < 4; ++r) {
#pragma unroll
            for (int off = 1; off < 16; off <<= 1) rs[r] += __shfl_xor(rs[r], off);
            l_i[r] = l_i[r] * alpha[r] + rs[r];
        }
#pragma unroll
        for (int nd = 0; nd < 4; ++nd)
#pragma unroll
            for (int r = 0; r < 4; ++r) oacc[nd][r] *= alpha[r];

        const short8 ap0 = *(const short8*)&Ps[w][c * 72 + 0 * 32 + quad * 8];
        const short8 ap1 = *(const short8*)&Ps[w][c * 72 + 1 * 32 + quad * 8];
#pragma unroll
        for (int nd = 0; nd < 4; ++nd) {
            const short8 bv0 = *(const short8*)&Vs[(nd * 2 + 0) * 512 + lane * 8];
            const short8 bv1 = *(const short8*)&Vs[(nd * 2 + 1) * 512 + lane * 8];
            oacc[nd] = __builtin_amdgcn_mfma_f32_16x16x32_bf16(ap0, bv0, oacc[nd], 0, 0, 0);
            oacc[nd] = __builtin_amdgcn_mfma_f32_16x16x32_bf16(ap1, bv1, oacc[nd], 0, 0, 0);
        }
        __syncthreads();
    }

    // epilogue: Yb[b][t][h*64 + d] bf16
#pragma unroll
    for (int r = 0; r < 4; ++r) {
        const float inv = 1.f / l_i[r];
        const int trow = i0 + w * 16 + quad * 4 + r;
        unsigned short* yb = Yb + ((size_t)b * TT + trow) * CC + h * HDD;
#pragma unroll
        for (int nd = 0; nd < 4; ++nd)
            yb[nd * 16 + c] = f2bf(oacc[nd][r] * inv);
    }
}

// ---------------------------------------------------------------------------
// Kernel 4: out = Yb @ Wpb^T + b_proj via MFMA (R4/R6-proven).
// ---------------------------------------------------------------------------
__global__ __launch_bounds__(256, 2) void gemm_proj_mfma(
    const unsigned short* __restrict__ Yb, const unsigned short* __restrict__ Wp,
    const float* __restrict__ bias, float* __restrict__ out)
{
    __shared__ __align__(16) unsigned short lds[24 * 512];

    const int tid = threadIdx.x;
    const int w = tid >> 6, lane = tid & 63;
    const int c = lane & 15, quad = lane >> 4;
    const int wm = w >> 1, wn = w & 1;
    const int bm = blockIdx.y * 64, bn = blockIdx.x * 128;

    const unsigned short* pp[6];
#pragma unroll
    for (int l = 0; l < 6; ++l) {
        const int ci = w * 6 + l;
        if (ci < 8) {
            const int m16 = ci >> 1, kk = ci & 1;
            pp[l] = Yb + (size_t)(bm + m16 * 16 + c) * 512 + kk * 32 + quad * 8;
        } else {
            const int cb = ci - 8, n16 = cb >> 1, kk = cb & 1;
            pp[l] = Wp + (size_t)(bn + n16 * 16 + c) * 512 + kk * 32 + quad * 8;
        }
    }

    f32x4 acc[2][4];
#pragma unroll
    for (int i = 0; i < 2; ++i)
#pragma unroll
        for (int j = 0; j < 4; ++j) acc[i][j] = (f32x4){0.f, 0.f, 0.f, 0.f};

    short8 pre[6];
#pragma unroll
    for (int l = 0; l < 6; ++l) pre[l] = *(const short8*)pp[l];

    for (int k0 = 0; k0 < 512; k0 += 64) {
        __syncthreads();
#pragma unroll
        for (int l = 0; l < 6; ++l)
            *(short8*)&lds[(w * 6 + l) * 512 + lane * 8] = pre[l];
        __syncthreads();
        if (k0 + 64 < 512) {
#pragma unroll
            for (int l = 0; l < 6; ++l)
                pre[l] = *(const short8*)(pp[l] + k0 + 64);
        }
#pragma unroll
        for (int kk = 0; kk < 2; ++kk) {
            short8 af[2], bfr[4];
#pragma unroll
            for (int i = 0; i < 2; ++i)
                af[i] = *(const short8*)&lds[((wm * 2 + i) * 2 + kk) * 512 + lane * 8];
#pragma unroll
            for (int j = 0; j < 4; ++j)
                bfr[j] = *(const short8*)&lds[(8 + (wn * 4 + j) * 2 + kk) * 512 + lane * 8];
#pragma unroll
            for (int i = 0; i < 2; ++i)
#pragma unroll
                for (int j = 0; j < 4; ++j)
                    acc[i][j] = __builtin_amdgcn_mfma_f32_16x16x32_bf16(
                        af[i], bfr[j], acc[i][j], 0, 0, 0);
        }
    }

#pragma unroll
    for (int j = 0; j < 4; ++j) {
        const int n = bn + wn * 64 + j * 16 + c;
        const float bj = bias[n];
#pragma unroll
        for (int i = 0; i < 2; ++i)
#pragma unroll
            for (int r = 0; r < 4; ++r) {
                const int m = bm + wm * 32 + i * 16 + quad * 4 + r;
                out[(size_t)m * 512 + n] = acc[i][j][r] + bj;
            }
    }
}

// ---------------------------------------------------------------------------
extern "C" void kernel_launch(void* const* d_in, const int* in_sizes, int n_in,
                              void* d_out, int out_size, void* d_ws, size_t ws_size,
                              hipStream_t stream)
{
    const float* x      = (const float*)d_in[0];
    const float* w_attn = (const float*)d_in[1];
    const float* b_attn = (const float*)d_in[2];
    const float* w_proj = (const float*)d_in[3];
    const float* b_proj = (const float*)d_in[4];
    const float* q_g    = (const float*)d_in[5];
    const float* q_b    = (const float*)d_in[6];
    const float* k_g    = (const float*)d_in[7];
    const float* k_b    = (const float*)d_in[8];
    const float* rel    = (const float*)d_in[9];
    float* out = (float*)d_out;

    // workspace: qkbuf bf16 8MB | Yb 4MB | VT 4MB | Relb 0.5 | Xb 4 | Wqb 1.5 |
    //   Wpb 0.5 | Stats fp32 64KB   (~22.6 MB). attn reads qkbuf -> Yb separate.
    unsigned short* qkbuf = (unsigned short*)d_ws;
    unsigned short* Yb   = qkbuf + (size_t)4096 * 1024;
    unsigned short* VT   = Yb + (size_t)4096 * 512;
    unsigned short* Relb = VT + (size_t)4096 * 512;
    unsigned short* Xb   = Relb + (size_t)512 * 512;
    unsigned short* Wqb  = Xb + (size_t)4096 * 512;
    unsigned short* Wpb  = Wqb + (size_t)1536 * 512;
    float* Stats = (float*)(Wpb + (size_t)512 * 512);

    zero_stats_k<<<16, 256, 0, stream>>>(Stats);
    cvt_all_k<<<3328, 256, 0, stream>>>(x, w_attn, w_proj, rel, Xb, Wqb, Wpb, Relb);
    gemm_qkv_mfma<<<dim3(12, 32), 256, 0, stream>>>(Xb, Wqb, b_attn, qkbuf, VT, Stats);
    attn_k<<<512, 256, 0, stream>>>(qkbuf, VT, Relb, Stats, q_g, q_b, k_g, k_b, Yb);
    gemm_proj_mfma<<<dim3(4, 64), 256, 0, stream>>>(Yb, Wpb, b_proj, out);
}